// Round 1
// baseline (51.247 us; speedup 1.0000x reference)
//
#include <hip/hip_runtime.h>

// out[m, n] = sum_d a[m, d] * T_d(x[n]),  T_d = Chebyshev via recurrence.
// N = 2097152, M = 32, DEG = 16. Write-BW-bound (~256 MB out).

#define DEG 16
#define M_ROWS 32
#define ELEMS_PER_THREAD 4

__global__ __launch_bounds__(256) void cheb_gemm_kernel(
    const float* __restrict__ x,
    const float* __restrict__ a,
    float* __restrict__ out,
    int n)
{
    const int i = (blockIdx.x * 256 + threadIdx.x) * ELEMS_PER_THREAD;
    if (i + ELEMS_PER_THREAD - 1 >= n) return;

    // Coalesced 16B load of 4 consecutive x values.
    const float4 xv = *reinterpret_cast<const float4*>(x + i);
    float xs[ELEMS_PER_THREAD] = {xv.x, xv.y, xv.z, xv.w};

    // Chebyshev basis T_0..T_15 for each of the 4 elements, in registers.
    float basis[ELEMS_PER_THREAD][DEG];
#pragma unroll
    for (int j = 0; j < ELEMS_PER_THREAD; ++j) {
        float t0 = 1.0f;
        float t1 = xs[j];
        basis[j][0] = t0;
        basis[j][1] = t1;
        const float two_x = xs[j] + xs[j];
#pragma unroll
        for (int k = 2; k < DEG; ++k) {
            float t2 = fmaf(two_x, t1, -t0);
            basis[j][k] = t2;
            t0 = t1;
            t1 = t2;
        }
    }

    // For each output row m: dot(a[m, :], basis[j, :]) then float4 store.
    // a[] addresses are wave-uniform -> scalar loads (s_load_dwordx16 per row).
#pragma unroll 4
    for (int m = 0; m < M_ROWS; ++m) {
        float acc0 = 0.0f, acc1 = 0.0f, acc2 = 0.0f, acc3 = 0.0f;
#pragma unroll
        for (int d = 0; d < DEG; ++d) {
            const float c = a[m * DEG + d];
            acc0 = fmaf(c, basis[0][d], acc0);
            acc1 = fmaf(c, basis[1][d], acc1);
            acc2 = fmaf(c, basis[2][d], acc2);
            acc3 = fmaf(c, basis[3][d], acc3);
        }
        float4* dst = reinterpret_cast<float4*>(out + (size_t)m * (size_t)n + i);
        *dst = make_float4(acc0, acc1, acc2, acc3);
    }
}

extern "C" void kernel_launch(void* const* d_in, const int* in_sizes, int n_in,
                              void* d_out, int out_size, void* d_ws, size_t ws_size,
                              hipStream_t stream) {
    const float* x = (const float*)d_in[0];
    const float* a = (const float*)d_in[1];
    float* out = (float*)d_out;
    const int n = in_sizes[0];  // 2097152

    const int threads = 256;
    const int elems_per_block = threads * ELEMS_PER_THREAD;  // 1024
    const int blocks = (n + elems_per_block - 1) / elems_per_block;  // 2048

    cheb_gemm_kernel<<<blocks, threads, 0, stream>>>(x, a, out, n);
}